// Round 1
// 1228.716 us; speedup vs baseline: 1.3489x; 1.3489x over previous
//
#include <hip/hip_runtime.h>

// Deep Kalman Filter, fully fused. Dims: X=1, Z=16, H=16, G=8, I=16, T=512, B=2048
//
// Design (latency-bound serial scan; wall time == one wave's serial chain):
//  - One wave (64 lanes) per batch element, grid = 2048, all waves resident.
//  - ALL uniform broadcasts via v_readlane -> SGPR (VALU port, ~4cy) instead of
//    __shfl/ds_bpermute (LDS pipe, ~120cy dependent latency). Only the 3
//    per-lane-divergent f/g/o gathers in the LSTM remain __shfl (one stage).
//  - Static software-pipelined rings (unroll-4, compile-time indices only):
//    eps prefetch +4 iters, x prefetch +4 iters, hbuf ds_read prefetch +1.
//  - dec/tr heads fused into the phase-2 loop (deletes the 2nd kernel, the
//    z/z_prev stash write and its uncoalesced re-read). Their instructions are
//    independent of the loop-carried z chain -> fill stall slots.
//  - Weight-register overlay by lane group: lanes 0-15 hold comb1/comb2/enc2
//    rows in wA/wB/wD; lanes 16-31 hold dec1+tr1/dec2/tr2 rows in the SAME
//    variables (88 weight VGPRs/lane total).
#define T_LEN 512
#define BATCH 2048
#define OUTW  66   // [mu_x(1), logvar_x(1), mu_z(16), logvar_z(16), mu_tr(16), logvar_tr(16)]

typedef unsigned short u16;
typedef unsigned int   u32;

__device__ __forceinline__ float bf2f(u16 u) {
    union { u32 i; float f; } v; v.i = ((u32)u) << 16; return v.f;
}
__device__ __forceinline__ u16 f2bf(float f) {
    union { u32 i; float f; } v; v.f = f;
    u32 x = v.i;
    return (u16)((x + 0x7fffu + ((x >> 16) & 1u)) >> 16);  // RNE
}
__device__ __forceinline__ float fexp2(float x) { return __builtin_amdgcn_exp2f(x); }
__device__ __forceinline__ float frcp(float x)  { return __builtin_amdgcn_rcpf(x); }
// tanh(x) = 2/(1+exp2(-2*log2e*x)) - 1 ; saturates correctly at +-1
__device__ __forceinline__ float ftanh(float x) {
    return fmaf(2.f, frcp(1.f + fexp2(-2.88539008f * x)), -1.f);
}
// wave-uniform broadcast through the scalar RF (cheap; NOT the LDS pipe)
__device__ __forceinline__ float rdl(float v, int l) {
    return __int_as_float(__builtin_amdgcn_readlane(__float_as_int(v), l));
}

// Inputs are float32 (proven in earlier rounds); keep runtime guard.
__device__ __forceinline__ float ldin(const void* p, int i, bool f32) {
    return f32 ? ((const float*)p)[i] : bf2f(((const u16*)p)[i]);
}

__device__ __forceinline__ bool detect_f32(const void* whh) {
    const u16* w = (const u16*)whh;
    int bad = 0;
    for (int i = (threadIdx.x & 63); i < 1024; i += 64) {
        int e = (w[i] >> 7) & 0xFF;
        bad |= (e > 125) ? 1 : 0;
    }
    return __any(bad) != 0;
}

__global__ __launch_bounds__(64, 2)
void dkf_fused_kernel(const void* __restrict__ x,
                      const void* __restrict__ eps_z,
                      const void* __restrict__ Wih,  const void* __restrict__ Whh,
                      const void* __restrict__ bih,  const void* __restrict__ bhh,
                      const void* __restrict__ cW1,  const void* __restrict__ cb1,
                      const void* __restrict__ cW2,  const void* __restrict__ cb2,
                      const void* __restrict__ eW1,  const void* __restrict__ eb1,
                      const void* __restrict__ eW2,  const void* __restrict__ eb2,
                      const void* __restrict__ dW1,  const void* __restrict__ db1,
                      const void* __restrict__ dW2,  const void* __restrict__ db2,
                      const void* __restrict__ tW1,  const void* __restrict__ tb1,
                      const void* __restrict__ tW2,  const void* __restrict__ tb2,
                      float* __restrict__ out)
{
    __shared__ u16 hbuf[T_LEN * 16];   // 16 KiB: h_seq (bf16) for this batch element

    const bool F32 = detect_f32(Whh);
    const int b    = blockIdx.x;
    const int lane = threadIdx.x;   // 0..63
    const int rr   = lane & 15;

    // ---------------- Phase 1: backward LSTM ----------------
    {
        const float wih_l  = ldin(Wih, lane, F32);                 // X_DIM == 1
        const float bias_l = ldin(bih, lane, F32) + ldin(bhh, lane, F32);
        float wh[16];
#pragma unroll
        for (int k = 0; k < 16; ++k) wh[k] = ldin(Whh, lane * 16 + k, F32);

        const bool  is_g = (lane >= 32) && (lane < 48);
        const float nls  = is_g ? -2.88539008f : -1.44269504f;
        const float scl  = is_g ? 2.f : 1.f;
        const float off  = is_g ? 1.f : 0.f;

        float h = 0.f, c = 0.f;
        float xr[4];
#pragma unroll
        for (int q = 0; q < 4; ++q) xr[q] = ldin(x, (T_LEN - 1 - q) * BATCH + b, F32);

        for (int t4 = 0; t4 < T_LEN / 4; ++t4) {
#pragma unroll
            for (int q = 0; q < 4; ++q) {
                const int t = T_LEN - 1 - t4 * 4 - q;
                // broadcast h (lanes 0..15 valid) into SGPRs
                float sh[16];
#pragma unroll
                for (int k = 0; k < 16; ++k) sh[k] = rdl(h, k);
                float a0 = fmaf(wih_l, xr[q], bias_l), a1 = 0.f, a2 = 0.f, a3 = 0.f;
#pragma unroll
                for (int k = 0; k < 16; k += 4) {
                    a0 = fmaf(wh[k],     sh[k],     a0);
                    a1 = fmaf(wh[k + 1], sh[k + 1], a1);
                    a2 = fmaf(wh[k + 2], sh[k + 2], a2);
                    a3 = fmaf(wh[k + 3], sh[k + 3], a3);
                }
                const float gate = (a0 + a1) + (a2 + a3);
                // sigmoid for i/f/o lanes, tanh for g lanes (scale trick)
                const float sgm = frcp(1.f + fexp2(nls * gate));
                const float av  = fmaf(scl, sgm, -off);
                // gather f/g/o onto lanes 0..15 (per-lane-divergent: keep __shfl)
                const float af = __shfl(av, (lane + 16) & 63, 64);
                const float ag = __shfl(av, (lane + 32) & 63, 64);
                const float ao = __shfl(av, (lane + 48) & 63, 64);
                c = fmaf(af, c, av * ag);      // lanes 0..15: sig(f)*c + sig(i)*tanh(g)
                h = ao * ftanh(c);             // lanes 0..15: sig(o)*tanh(c)
                if (lane < 16) hbuf[t * 16 + lane] = f2bf(h);
                // x prefetch ring (+4)
                const int tn = (t >= 4) ? (t - 4) : 0;
                xr[q] = ldin(x, tn * BATCH + b, F32);
            }
        }
    }
    __syncthreads();

    // ---------------- Phase 2: forward DKF scan + dec + tr (fused) ----------------
    const bool gA = (lane < 16);   // enc-chain lanes; lanes 16..31 = dec/tr lanes

    // wA: gA -> comb_W1 row rr (32 cols: [h|z]); gB -> [dec_W1 row | tr_W1 row]
    float wA[32];
#pragma unroll
    for (int k = 0; k < 32; ++k)
        wA[k] = gA ? ldin(cW1, rr * 32 + k, F32)
                   : (k < 16 ? ldin(dW1, rr * 16 + k, F32)
                             : ldin(tW1, rr * 16 + (k - 16), F32));
    // wB: gA -> comb_W2 row (lane&7); gB -> dec_W2 row (rr&1)
    float wB[16];
#pragma unroll
    for (int k = 0; k < 16; ++k)
        wB[k] = gA ? ldin(cW2, (lane & 7) * 16 + k, F32)
                   : ldin(dW2, (rr & 1) * 16 + k, F32);
    // wC: enc_W1 row rr (all lanes; only 0..15 used)
    float wC[8];
#pragma unroll
    for (int k = 0; k < 8; ++k) wC[k] = ldin(eW1, rr * 8 + k, F32);
    // wD: gA -> enc_W2 rows rr (mu) and rr+16 (lv); gB -> tr_W2 rows rr / rr+16
    float wD[32];
#pragma unroll
    for (int k = 0; k < 32; ++k) {
        const int row = (k < 16) ? rr : (rr + 16);
        const int col = k & 15;
        wD[k] = gA ? ldin(eW2, row * 16 + col, F32)
                   : ldin(tW2, row * 16 + col, F32);
    }
    const float bA1 = gA ? ldin(cb1, rr, F32)       : ldin(db1, rr, F32);
    const float bA2 =      ldin(tb1, rr, F32);
    const float bB  = gA ? ldin(cb2, lane & 7, F32) : ldin(db2, rr & 1, F32);
    const float bC  =      ldin(eb1, rr, F32);
    const float bD1 = gA ? ldin(eb2, rr, F32)       : ldin(tb2, rr, F32);
    const float bD2 = gA ? ldin(eb2, rr + 16, F32)  : ldin(tb2, rr + 16, F32);

    float sz[16];                      // z_prev broadcast (SGPRs), z0 = 0
#pragma unroll
    for (int k = 0; k < 16; ++k) sz[k] = 0.f;

    float epf[4];                      // eps prefetch ring (+4 iters)
#pragma unroll
    for (int q = 0; q < 4; ++q) epf[q] = ldin(eps_z, (q * BATCH + b) * 16 + rr, F32);
    u16 hr[4];                         // hbuf ds_read prefetch ring (+1 iter)
    hr[0] = hbuf[rr];

    for (int t4 = 0; t4 < T_LEN / 4; ++t4) {
#pragma unroll
        for (int q = 0; q < 4; ++q) {
            const int t = t4 * 4 + q;
            // prefetch next h row from LDS
            {
                const int tn = (t + 1 < T_LEN) ? (t + 1) : (T_LEN - 1);
                hr[(q + 1) & 3] = hbuf[tn * 16 + rr];
            }
            const float hv = bf2f(hr[q]);
            float sh[16];
#pragma unroll
            for (int k = 0; k < 16; ++k) sh[k] = rdl(hv, k);

            // shared z-part: pz = sum_k wA[16+k]*z_prev[k]
            //   gA: comb1 z-half     gB: tr1 pre-activation (tW1 @ z_prev)
            float p0 = 0.f, p1 = 0.f, p2 = 0.f, p3 = 0.f;
#pragma unroll
            for (int k = 0; k < 16; k += 4) {
                p0 = fmaf(wA[16 + k], sz[k],     p0);
                p1 = fmaf(wA[17 + k], sz[k + 1], p1);
                p2 = fmaf(wA[18 + k], sz[k + 2], p2);
                p3 = fmaf(wA[19 + k], sz[k + 3], p3);
            }
            const float pz = (p0 + p1) + (p2 + p3);
            // comb1 h-part (gA)
            float q0 = 0.f, q1 = 0.f, q2 = 0.f, q3 = 0.f;
#pragma unroll
            for (int k = 0; k < 16; k += 4) {
                q0 = fmaf(wA[k],     sh[k],     q0);
                q1 = fmaf(wA[k + 1], sh[k + 1], q1);
                q2 = fmaf(wA[k + 2], sh[k + 2], q2);
                q3 = fmaf(wA[k + 3], sh[k + 3], q3);
            }
            const float ph  = (q0 + q1) + (q2 + q3);
            const float a1v = ftanh(bA1 + ph + pz);   // comb1 out, lanes 0..15
            const float atv = ftanh(bA2 + pz);        // tr1 out, lanes 16..31

            float sa1[16], sat[16];
#pragma unroll
            for (int k = 0; k < 16; ++k) { sa1[k] = rdl(a1v, k); sat[k] = rdl(atv, 16 + k); }

            // comb2 (lanes 0..7): g = cb2 + cW2 @ a1
            float g0 = bB, g1 = 0.f, g2 = 0.f, g3 = 0.f;
#pragma unroll
            for (int k = 0; k < 16; k += 4) {
                g0 = fmaf(wB[k],     sa1[k],     g0);
                g1 = fmaf(wB[k + 1], sa1[k + 1], g1);
                g2 = fmaf(wB[k + 2], sa1[k + 2], g2);
                g3 = fmaf(wB[k + 3], sa1[k + 3], g3);
            }
            const float gv = (g0 + g1) + (g2 + g3);
            float sg[8];
#pragma unroll
            for (int k = 0; k < 8; ++k) sg[k] = rdl(gv, k);

            // enc1 (lanes 0..15)
            float r0 = bC, r1 = 0.f;
#pragma unroll
            for (int k = 0; k < 8; k += 2) {
                r0 = fmaf(wC[k],     sg[k],     r0);
                r1 = fmaf(wC[k + 1], sg[k + 1], r1);
            }
            const float e1 = ftanh(r0 + r1);
            float se1[16];
#pragma unroll
            for (int k = 0; k < 16; ++k) se1[k] = rdl(e1, k);

            // enc2 (gA: mu_z, logvar_z) and tr2 (gB: mu_tr, logvar_tr), sharing wD
            float m0 = bD1, m1 = 0.f, v0 = bD2, v1 = 0.f;   // gA
            float n0 = bD1, n1 = 0.f, w0 = bD2, w1 = 0.f;   // gB
#pragma unroll
            for (int k = 0; k < 16; k += 2) {
                m0 = fmaf(wD[k],      se1[k],     m0);
                m1 = fmaf(wD[k + 1],  se1[k + 1], m1);
                v0 = fmaf(wD[16 + k], se1[k],     v0);
                v1 = fmaf(wD[17 + k], se1[k + 1], v1);
                n0 = fmaf(wD[k],      sat[k],     n0);
                n1 = fmaf(wD[k + 1],  sat[k + 1], n1);
                w0 = fmaf(wD[16 + k], sat[k],     w0);
                w1 = fmaf(wD[17 + k], sat[k + 1], w1);
            }
            const float mu  = m0 + m1;
            const float lv  = v0 + v1;
            const float mtr = n0 + n1;
            const float ltr = w0 + w1;

            // reparameterize on lanes 0..15: z = mu + eps * exp(0.5*logvar)
            const float lvc = fminf(lv, 40.f);
            const float zv  = fmaf(epf[q], fexp2(0.72134752f * lvc), mu);

            const size_t rb = (size_t)(t * BATCH + b) * OUTW;
            if (lane < 16) {
                out[rb + 2 + lane]  = mu;
                out[rb + 18 + lane] = lv;
            } else if (lane < 32) {
                out[rb + 34 + rr] = mtr;
                out[rb + 50 + rr] = ltr;
            }

            // z broadcast (serves next iter's comb1/tr1 AND this iter's dec1)
#pragma unroll
            for (int k = 0; k < 16; ++k) sz[k] = rdl(zv, k);

            // dec1 (lanes 16..31): ad = tanh(db1 + dW1 @ z)
            float d0 = bA1, d1 = 0.f, d2 = 0.f, d3 = 0.f;
#pragma unroll
            for (int k = 0; k < 16; k += 4) {
                d0 = fmaf(wA[k],     sz[k],     d0);
                d1 = fmaf(wA[k + 1], sz[k + 1], d1);
                d2 = fmaf(wA[k + 2], sz[k + 2], d2);
                d3 = fmaf(wA[k + 3], sz[k + 3], d3);
            }
            const float ad = ftanh((d0 + d1) + (d2 + d3));
            float sad[16];
#pragma unroll
            for (int k = 0; k < 16; ++k) sad[k] = rdl(ad, 16 + k);

            // dec2 (lanes 16..17): [mu_x, logvar_x]
            float o0 = bB, o1 = 0.f, o2 = 0.f, o3 = 0.f;
#pragma unroll
            for (int k = 0; k < 16; k += 4) {
                o0 = fmaf(wB[k],     sad[k],     o0);
                o1 = fmaf(wB[k + 1], sad[k + 1], o1);
                o2 = fmaf(wB[k + 2], sad[k + 2], o2);
                o3 = fmaf(wB[k + 3], sad[k + 3], o3);
            }
            const float ox = (o0 + o1) + (o2 + o3);
            if (lane >= 16 && lane < 18) out[rb + (lane - 16)] = ox;

            // eps prefetch ring (+4)
            {
                const int tn = (t + 4 < T_LEN) ? (t + 4) : (T_LEN - 1);
                epf[q] = ldin(eps_z, (tn * BATCH + b) * 16 + rr, F32);
            }
        }
    }
}

extern "C" void kernel_launch(void* const* d_in, const int* in_sizes, int n_in,
                              void* d_out, int out_size, void* d_ws, size_t ws_size,
                              hipStream_t stream) {
    (void)in_sizes; (void)n_in; (void)out_size; (void)d_ws; (void)ws_size;
    const void* x     = d_in[0];
    const void* eps_z = d_in[1];
    const void* Wih   = d_in[2];
    const void* Whh   = d_in[3];
    const void* bih   = d_in[4];
    const void* bhh   = d_in[5];
    const void* cW1   = d_in[6];
    const void* cb1   = d_in[7];
    const void* cW2   = d_in[8];
    const void* cb2   = d_in[9];
    const void* eW1   = d_in[10];
    const void* eb1   = d_in[11];
    const void* eW2   = d_in[12];
    const void* eb2   = d_in[13];
    const void* dW1   = d_in[14];
    const void* db1   = d_in[15];
    const void* dW2   = d_in[16];
    const void* db2   = d_in[17];
    const void* tW1   = d_in[18];
    const void* tb1   = d_in[19];
    const void* tW2   = d_in[20];
    const void* tb2   = d_in[21];

    float* out = (float*)d_out;

    dkf_fused_kernel<<<BATCH, 64, 0, stream>>>(
        x, eps_z, Wih, Whh, bih, bhh,
        cW1, cb1, cW2, cb2, eW1, eb1, eW2, eb2,
        dW1, db1, dW2, db2, tW1, tb1, tW2, tb2,
        out);
}

// Round 2
// 1140.234 us; speedup vs baseline: 1.4536x; 1.0776x over previous
//
#include <hip/hip_runtime.h>

// Deep Kalman Filter via MFMA. Dims: X=1, Z=16, H=16, G=8, I=16, T=512, B=2048
//
// Architecture: 16 batch elements per wave (batch on the mfma N dimension),
// 128 blocks x 64 threads, one wave per block. Wall time = one wave's serial
// chain over 1024 timesteps; each tiny matvec is ONE v_mfma_f32_16x16x32_bf16
// (vs ~30 wave-wide VALU ops per layer in the readlane version).
//
// Layouts (guide-verified for 16x16x32 bf16):
//   A frag: row = lane&15, k = 8*(lane>>4)+[0..8)   (weights, preloaded)
//   B frag: col = lane&15, k = 8*(lane>>4)+[0..8)   (activations, batch=col)
//   C/D   : col = lane&15, row = 4*(lane>>4)+reg    (f32 accum)
// D->B relayout: 2x v_cvt_pk_bf16_f32 + 4x ds_bpermute w/ constant addresses.
//
// Precision: recurrence paths (LSTM h, DKF z chain) carry SPLIT bf16 (hi+lo,
// 3-term products, lo*lo dropped) => ~f32 accuracy, no compounding over 512
// steps. Leaf heads (dec/tr) use single-bf16 weights (non-compounding).
// h_seq stashed hi+lo in out channels 34..49 (f32 slots reused as bf16x2
// words), overwritten later by mu_tr/logvar_tr of the same row.
#define T_LEN 512
#define BATCH 2048
#define OUTW  66   // [mu_x(1), logvar_x(1), mu_z(16), logvar_z(16), mu_tr(16), logvar_tr(16)]

typedef unsigned int u32;
typedef short v8s __attribute__((ext_vector_type(8)));   // 8 bf16 = A/B frag
typedef float v4f __attribute__((ext_vector_type(4)));   // C/D frag
typedef float v2f __attribute__((ext_vector_type(2)));
typedef u32   v2u __attribute__((ext_vector_type(2)));

union FragU { v8s s; u32 w[4]; };

__device__ __forceinline__ float fexp2(float x){ return __builtin_amdgcn_exp2f(x); }
__device__ __forceinline__ float frcp (float x){ return __builtin_amdgcn_rcpf(x); }
// tanh(x) = 2/(1+exp2(-2*log2e*x)) - 1 ; saturates correctly at +-1
__device__ __forceinline__ float ftanh(float x){
    return fmaf(2.f, frcp(1.f + fexp2(-2.88539008f * x)), -1.f);
}
__device__ __forceinline__ float fsig(float x){
    return frcp(1.f + fexp2(-1.44269504f * x));
}
__device__ __forceinline__ u32 cvtpk(float lo, float hi){
    u32 r; asm("v_cvt_pk_bf16_f32 %0, %1, %2" : "=v"(r) : "v"(lo), "v"(hi)); return r;
}
__device__ __forceinline__ float ubf_lo(u32 w){ union{u32 i; float f;} v; v.i = w << 16;         return v.f; }
__device__ __forceinline__ float ubf_hi(u32 w){ union{u32 i; float f;} v; v.i = w & 0xffff0000u; return v.f; }
__device__ __forceinline__ u32 bperm(int addr, u32 v){ return (u32)__builtin_amdgcn_ds_bpermute(addr, (int)v); }
// split f32 pair -> hi bf16x2 word + lo (residual) bf16x2 word
__device__ __forceinline__ void packpair(float a, float b, u32& wh, u32& wl){
    u32 h = cvtpk(a, b);
    wl = cvtpk(a - ubf_lo(h), b - ubf_hi(h));
    wh = h;
}
#define MFMA(A,B,C) __builtin_amdgcn_mfma_f32_16x16x32_bf16((A),(B),(C),0,0,0)

// Load weight A-fragment, split hi+lo. W row-major [R x ld], use cols [0,C).
__device__ __forceinline__ void loadAsplit(const float* W, int ld, int R, int C,
                                           v8s& hi, v8s& lo){
    const int r = threadIdx.x & 15, G = threadIdx.x >> 4;
    FragU H, L;
#pragma unroll
    for (int p = 0; p < 4; ++p){
        const int k0 = 8*G + 2*p;
        float a = (r < R && k0     < C) ? W[r*ld + k0]     : 0.f;
        float b = (r < R && k0 + 1 < C) ? W[r*ld + k0 + 1] : 0.f;
        packpair(a, b, H.w[p], L.w[p]);
    }
    hi = H.s; lo = L.s;
}
// Single-precision (hi only) A-fragment for leaf weights.
__device__ __forceinline__ v8s loadA1(const float* W, int ld, int R, int C){
    const int r = threadIdx.x & 15, G = threadIdx.x >> 4;
    FragU H;
#pragma unroll
    for (int p = 0; p < 4; ++p){
        const int k0 = 8*G + 2*p;
        float a = (r < R && k0     < C) ? W[r*ld + k0]     : 0.f;
        float b = (r < R && k0 + 1 < C) ? W[r*ld + k0 + 1] : 0.f;
        H.w[p] = cvtpk(a, b);
    }
    return H.s;
}
// Bias as C-fragment: lane reg j holds bias[4*(lane>>4)+j] (0 beyond R).
__device__ __forceinline__ v4f loadCbias(const float* bsrc, int R){
    const int m = threadIdx.x >> 4;
    v4f c;
#pragma unroll
    for (int j = 0; j < 4; ++j){
        const int idx = 4*m + j;
        c[j] = (idx < R) ? bsrc[idx] : 0.f;
    }
    return c;
}
// D fragment (f32, rows 4m+[0..4) of col c) -> split bf16 B fragments.
// alo = 4*(32*G + c), ahi = alo+64 (precomputed). uz: lanes G>=2 get zeros
// (B rows 16..31 are zero padding).
__device__ __forceinline__ void splitB(v4f d, int alo, int ahi, bool uz,
                                       v8s& bh, v8s& bl){
    u32 h0, l0, h1, l1;
    packpair(d[0], d[1], h0, l0);
    packpair(d[2], d[3], h1, l1);
    FragU H, L;
    H.w[0] = bperm(alo, h0); H.w[1] = bperm(alo, h1);
    H.w[2] = bperm(ahi, h0); H.w[3] = bperm(ahi, h1);
    L.w[0] = bperm(alo, l0); L.w[1] = bperm(alo, l1);
    L.w[2] = bperm(ahi, l0); L.w[3] = bperm(ahi, l1);
    if (uz){
#pragma unroll
        for (int p = 0; p < 4; ++p){ H.w[p] = 0u; L.w[p] = 0u; }
    }
    bh = H.s; bl = L.s;
}
__device__ __forceinline__ v4f tanh4(v4f a){
    v4f r;
#pragma unroll
    for (int j = 0; j < 4; ++j) r[j] = ftanh(a[j]);
    return r;
}
__device__ __forceinline__ void st2(float* p, float a, float b){
    v2f v; v[0] = a; v[1] = b; *(v2f*)p = v;
}
// Read stashed h (hi+lo bf16 words) for timestep t directly as B-fragments.
__device__ __forceinline__ void loadHfrag(const float* out, int t, int bc, int G,
                                          v8s& hh, v8s& hl){
    if (G < 2){
        const float* o = out + (size_t)(t*BATCH + bc) * OUTW;
        v2u a0 = *(const v2u*)(o + 34 + 4*G);
        v2u a1 = *(const v2u*)(o + 36 + 4*G);
        v2u b0 = *(const v2u*)(o + 42 + 4*G);
        v2u b1 = *(const v2u*)(o + 44 + 4*G);
        FragU H, L;
        H.w[0]=a0[0]; H.w[1]=a0[1]; H.w[2]=a1[0]; H.w[3]=a1[1];
        L.w[0]=b0[0]; L.w[1]=b0[1]; L.w[2]=b1[0]; L.w[3]=b1[1];
        hh = H.s; hl = L.s;
    } else {
        FragU Z; Z.w[0]=Z.w[1]=Z.w[2]=Z.w[3]=0u;
        hh = Z.s; hl = Z.s;
    }
}

__global__ __launch_bounds__(64)
void dkf_mfma_kernel(const float* __restrict__ x,   const float* __restrict__ eps_z,
                     const float* __restrict__ Wih, const float* __restrict__ Whh,
                     const float* __restrict__ bih, const float* __restrict__ bhh,
                     const float* __restrict__ cW1, const float* __restrict__ cb1,
                     const float* __restrict__ cW2, const float* __restrict__ cb2,
                     const float* __restrict__ eW1, const float* __restrict__ eb1,
                     const float* __restrict__ eW2, const float* __restrict__ eb2,
                     const float* __restrict__ dW1, const float* __restrict__ db1,
                     const float* __restrict__ dW2, const float* __restrict__ db2,
                     const float* __restrict__ tW1, const float* __restrict__ tb1,
                     const float* __restrict__ tW2, const float* __restrict__ tb2,
                     float* __restrict__ out)
{
    const int lane = threadIdx.x;
    const int c    = lane & 15;      // batch column within group
    const int G    = lane >> 4;      // k-subgroup / D-row subgroup
    const int b0   = blockIdx.x * 16;
    const int bc   = b0 + c;
    const bool uz  = (G >= 2);
    const int alo  = 4 * (32*G + c);
    const int ahi  = alo + 64;

    // ================= Phase 1: backward LSTM =================
    {
        v8s whT_h[4], whT_l[4];
#pragma unroll
        for (int g = 0; g < 4; ++g)
            loadAsplit(Whh + 256*g, 16, 16, 16, whT_h[g], whT_l[g]);
        v4f bc4[4];
#pragma unroll
        for (int g = 0; g < 4; ++g){
            v4f t;
#pragma unroll
            for (int j = 0; j < 4; ++j){
                const int idx = 16*g + 4*G + j;
                t[j] = bih[idx] + bhh[idx];
            }
            bc4[g] = t;
        }
        float wihr[4][4];
#pragma unroll
        for (int g = 0; g < 4; ++g)
#pragma unroll
            for (int j = 0; j < 4; ++j) wihr[g][j] = Wih[16*g + 4*G + j];

        v4f cst = {0.f, 0.f, 0.f, 0.f};
        FragU Z0; Z0.w[0]=Z0.w[1]=Z0.w[2]=Z0.w[3]=0u;
        v8s hhi = Z0.s, hlo = Z0.s;
        float xv[2];
        xv[0] = x[(T_LEN-1)*BATCH + bc];
        xv[1] = x[(T_LEN-2)*BATCH + bc];

        for (int t2 = 0; t2 < T_LEN/2; ++t2){
#pragma unroll
            for (int q = 0; q < 2; ++q){
                const int t = T_LEN - 1 - 2*t2 - q;
                // gates = (Whh_hi+Whh_lo) @ (h_hi+h_lo) + bias   (lo*lo dropped)
                v4f di = MFMA(whT_h[0], hhi, bc4[0]); di = MFMA(whT_h[0], hlo, di); di = MFMA(whT_l[0], hhi, di);
                v4f df = MFMA(whT_h[1], hhi, bc4[1]); df = MFMA(whT_h[1], hlo, df); df = MFMA(whT_l[1], hhi, df);
                v4f dg = MFMA(whT_h[2], hhi, bc4[2]); dg = MFMA(whT_h[2], hlo, dg); dg = MFMA(whT_l[2], hhi, dg);
                v4f doo= MFMA(whT_h[3], hhi, bc4[3]); doo= MFMA(whT_h[3], hlo, doo); doo= MFMA(whT_l[3], hhi, doo);
                // x rank-1 (X_DIM == 1), f32
#pragma unroll
                for (int j = 0; j < 4; ++j){
                    di[j]  = fmaf(wihr[0][j], xv[q], di[j]);
                    df[j]  = fmaf(wihr[1][j], xv[q], df[j]);
                    dg[j]  = fmaf(wihr[2][j], xv[q], dg[j]);
                    doo[j] = fmaf(wihr[3][j], xv[q], doo[j]);
                }
                v4f hv;
#pragma unroll
                for (int j = 0; j < 4; ++j){
                    const float si = fsig(di[j]);
                    const float sf = fsig(df[j]);
                    const float tg = ftanh(dg[j]);
                    const float so = fsig(doo[j]);
                    cst[j] = fmaf(sf, cst[j], si * tg);
                    hv[j]  = so * ftanh(cst[j]);
                }
                // split h -> hi/lo words, stash, relayout to B-frags
                u32 h0, l0, h1, l1;
                packpair(hv[0], hv[1], h0, l0);
                packpair(hv[2], hv[3], h1, l1);
                {
                    float* o = out + (size_t)(t*BATCH + bc) * OUTW;
                    v2u sh; sh[0] = h0; sh[1] = h1;
                    v2u sl; sl[0] = l0; sl[1] = l1;
                    *(v2u*)(o + 34 + 2*G) = sh;
                    *(v2u*)(o + 42 + 2*G) = sl;
                }
                FragU H, L;
                H.w[0] = bperm(alo, h0); H.w[1] = bperm(alo, h1);
                H.w[2] = bperm(ahi, h0); H.w[3] = bperm(ahi, h1);
                L.w[0] = bperm(alo, l0); L.w[1] = bperm(alo, l1);
                L.w[2] = bperm(ahi, l0); L.w[3] = bperm(ahi, l1);
                if (uz){
#pragma unroll
                    for (int p = 0; p < 4; ++p){ H.w[p] = 0u; L.w[p] = 0u; }
                }
                hhi = H.s; hlo = L.s;
                // x prefetch ring (+2)
                const int tn = (t >= 2) ? (t - 2) : 0;
                xv[q] = x[tn*BATCH + bc];
            }
        }
    }

    __threadfence();   // drain phase-1 stash stores before cross-lane readback

    // ================= Phase 2: forward DKF scan (fused heads) =================
    // Recurrence-path weights: split hi+lo. Leaf weights: single bf16.
    v8s aC1h_h, aC1h_l; loadAsplit(cW1,       32, 16, 16, aC1h_h, aC1h_l);
    v8s aC1z_h, aC1z_l; loadAsplit(cW1 + 16,  32, 16, 16, aC1z_h, aC1z_l);
    v8s aC2_h,  aC2_l;  loadAsplit(cW2,       16,  8, 16, aC2_h,  aC2_l);
    v8s aE1_h,  aE1_l;  loadAsplit(eW1,        8, 16,  8, aE1_h,  aE1_l);
    v8s aE2m_h, aE2m_l; loadAsplit(eW2,       16, 16, 16, aE2m_h, aE2m_l);
    v8s aE2v_h, aE2v_l; loadAsplit(eW2 + 256, 16, 16, 16, aE2v_h, aE2v_l);
    v8s aD1  = loadA1(dW1,       16, 16, 16);
    v8s aD2  = loadA1(dW2,       16,  2, 16);
    v8s aT1  = loadA1(tW1,       16, 16, 16);
    v8s aT2m = loadA1(tW2,       16, 16, 16);
    v8s aT2v = loadA1(tW2 + 256, 16, 16, 16);
    const v4f bC1  = loadCbias(cb1, 16);
    const v4f bC2  = loadCbias(cb2,  8);
    const v4f bE1  = loadCbias(eb1, 16);
    const v4f bE2m = loadCbias(eb2, 16);
    const v4f bE2v = loadCbias(eb2 + 16, 16);
    const v4f bD1  = loadCbias(db1, 16);
    const v4f bD2  = loadCbias(db2,  2);
    const v4f bT1  = loadCbias(tb1, 16);
    const v4f bT2m = loadCbias(tb2, 16);
    const v4f bT2v = loadCbias(tb2 + 16, 16);

    FragU Z1; Z1.w[0]=Z1.w[1]=Z1.w[2]=Z1.w[3]=0u;
    v8s zh = Z1.s, zl = Z1.s;       // z_prev split frags; z0 = 0

    v8s hhr[2], hlr[2];
    v4f epr[2];
    loadHfrag(out, 0, bc, G, hhr[0], hlr[0]);
    loadHfrag(out, 1, bc, G, hhr[1], hlr[1]);
    epr[0] = *(const v4f*)(eps_z + (size_t)(0*BATCH + bc)*16 + 4*G);
    epr[1] = *(const v4f*)(eps_z + (size_t)(1*BATCH + bc)*16 + 4*G);

    for (int t2 = 0; t2 < T_LEN/2; ++t2){
#pragma unroll
        for (int q = 0; q < 2; ++q){
            const int t = 2*t2 + q;
            float* o = out + (size_t)(t*BATCH + bc) * OUTW;
            const v8s hh = hhr[q], hl = hlr[q];
            const v4f ep = epr[q];
            // prefetch (+2)
            {
                int tn = t + 2; if (tn >= T_LEN) tn = T_LEN - 1;
                loadHfrag(out, tn, bc, G, hhr[q], hlr[q]);
                epr[q] = *(const v4f*)(eps_z + (size_t)(tn*BATCH + bc)*16 + 4*G);
            }
            // ---- tr branch (uses z_prev) ----
            v4f dt1 = MFMA(aT1, zh, bT1); dt1 = MFMA(aT1, zl, dt1);
            v4f at  = tanh4(dt1);
            v8s ath, atl; splitB(at, alo, ahi, uz, ath, atl);
            v4f dmt = MFMA(aT2m, ath, bT2m); dmt = MFMA(aT2m, atl, dmt);
            v4f dlt = MFMA(aT2v, ath, bT2v); dlt = MFMA(aT2v, atl, dlt);
            // ---- main chain ----
            v4f d1 = MFMA(aC1h_h, hh, bC1);
            d1 = MFMA(aC1h_h, hl, d1);
            d1 = MFMA(aC1h_l, hh, d1);
            d1 = MFMA(aC1z_h, zh, d1);
            d1 = MFMA(aC1z_h, zl, d1);
            d1 = MFMA(aC1z_l, zh, d1);
            v4f a1 = tanh4(d1);
            v8s a1h, a1l; splitB(a1, alo, ahi, uz, a1h, a1l);
            v4f d2 = MFMA(aC2_h, a1h, bC2); d2 = MFMA(aC2_h, a1l, d2); d2 = MFMA(aC2_l, a1h, d2);
            v8s gh, gl; splitB(d2, alo, ahi, uz, gh, gl);
            v4f d3 = MFMA(aE1_h, gh, bE1); d3 = MFMA(aE1_h, gl, d3); d3 = MFMA(aE1_l, gh, d3);
            v4f e1 = tanh4(d3);
            v8s e1h, e1l; splitB(e1, alo, ahi, uz, e1h, e1l);
            v4f dmu = MFMA(aE2m_h, e1h, bE2m); dmu = MFMA(aE2m_h, e1l, dmu); dmu = MFMA(aE2m_l, e1h, dmu);
            v4f dlv = MFMA(aE2v_h, e1h, bE2v); dlv = MFMA(aE2v_h, e1l, dlv); dlv = MFMA(aE2v_l, e1h, dlv);
            // reparameterize: z = mu + eps * exp(0.5*logvar)
            v4f zv;
#pragma unroll
            for (int j = 0; j < 4; ++j){
                const float s = fexp2(0.72134752f * fminf(dlv[j], 40.f));
                zv[j] = fmaf(ep[j], s, dmu[j]);
            }
            splitB(zv, alo, ahi, uz, zh, zl);   // becomes z_prev for next iter
            // ---- dec branch (uses new z) ----
            v4f dd1 = MFMA(aD1, zh, bD1); dd1 = MFMA(aD1, zl, dd1);
            v4f ad  = tanh4(dd1);
            v8s adh, adl; splitB(ad, alo, ahi, uz, adh, adl);
            v4f dd2 = MFMA(aD2, adh, bD2); dd2 = MFMA(aD2, adl, dd2);
            // ---- stores ----
            st2(o +  2 + 4*G, dmu[0], dmu[1]); st2(o +  4 + 4*G, dmu[2], dmu[3]);
            st2(o + 18 + 4*G, dlv[0], dlv[1]); st2(o + 20 + 4*G, dlv[2], dlv[3]);
            st2(o + 34 + 4*G, dmt[0], dmt[1]); st2(o + 36 + 4*G, dmt[2], dmt[3]);
            st2(o + 50 + 4*G, dlt[0], dlt[1]); st2(o + 52 + 4*G, dlt[2], dlt[3]);
            if (lane < 16) st2(o, dd2[0], dd2[1]);   // mu_x, logvar_x (rows 0,1)
        }
    }
}

extern "C" void kernel_launch(void* const* d_in, const int* in_sizes, int n_in,
                              void* d_out, int out_size, void* d_ws, size_t ws_size,
                              hipStream_t stream) {
    (void)in_sizes; (void)n_in; (void)out_size; (void)d_ws; (void)ws_size;
    const float* x     = (const float*)d_in[0];
    const float* eps_z = (const float*)d_in[1];
    const float* Wih   = (const float*)d_in[2];
    const float* Whh   = (const float*)d_in[3];
    const float* bih   = (const float*)d_in[4];
    const float* bhh   = (const float*)d_in[5];
    const float* cW1   = (const float*)d_in[6];
    const float* cb1   = (const float*)d_in[7];
    const float* cW2   = (const float*)d_in[8];
    const float* cb2   = (const float*)d_in[9];
    const float* eW1   = (const float*)d_in[10];
    const float* eb1   = (const float*)d_in[11];
    const float* eW2   = (const float*)d_in[12];
    const float* eb2   = (const float*)d_in[13];
    const float* dW1   = (const float*)d_in[14];
    const float* db1   = (const float*)d_in[15];
    const float* dW2   = (const float*)d_in[16];
    const float* db2   = (const float*)d_in[17];
    const float* tW1   = (const float*)d_in[18];
    const float* tb1   = (const float*)d_in[19];
    const float* tW2   = (const float*)d_in[20];
    const float* tb2   = (const float*)d_in[21];

    dkf_mfma_kernel<<<BATCH/16, 64, 0, stream>>>(
        x, eps_z, Wih, Whh, bih, bhh,
        cW1, cb1, cW2, cb2, eW1, eb1, eW2, eb2,
        dW1, db1, dW2, db2, tW1, tb1, tW2, tb2,
        (float*)d_out);
}

// Round 3
// 1003.826 us; speedup vs baseline: 1.6512x; 1.1359x over previous
//
#include <hip/hip_runtime.h>

// Deep Kalman Filter via MFMA + permlane swaps (no LDS pipe in the loop).
// Dims: X=1, Z=16, H=16, G=8, I=16, T=512, B=2048
//
// 16 batch elements per wave (batch on the mfma N dim), 128 blocks x 64 thr.
// Wall time = one wave's serial chain over 1024 timesteps.
//
// Layouts (guide-verified for 16x16x32 bf16):
//   A frag: row = lane&15, k = 8*(lane>>4)+[0..8)
//   B frag: col = lane&15, k = 8*(lane>>4)+[0..8)
//   C/D   : col = lane&15, row = 4*(lane>>4)+reg
//
// Precision scheme: activations split x = x_hi + x_lo (bf16 each). B-frag
// carries [x_hi | x_lo] in the two K-halves. Split-weight layers use
// A1=[W_hi|W_hi], A2=[W_lo|0]: y = W_hi*(x_hi+x_lo) + W_lo*x_hi in 2 MFMAs.
// Leaf layers use A=[W|W]: y = W*(x_hi+x_lo) in 1 MFMA.
//
// D->B relayout: 4x v_cvt_pk_bf16_f32 + residual subtract + 4 permlane swaps
// (VALU pipe, ~25cy chain) -- replaces r2's 8x ds_bpermute (~150cy + 7.3M
// bank conflicts).
#define T_LEN 512
#define BATCH 2048
#define OUTW  66   // [mu_x(1), logvar_x(1), mu_z(16), logvar_z(16), mu_tr(16), logvar_tr(16)]

typedef unsigned int u32;
typedef short v8s __attribute__((ext_vector_type(8)));   // 8 bf16 = A/B frag
typedef float v4f __attribute__((ext_vector_type(4)));   // C/D frag
typedef float v2f __attribute__((ext_vector_type(2)));
typedef u32   v2u __attribute__((ext_vector_type(2)));

union FragU { v8s s; u32 w[4]; };

__device__ __forceinline__ float fexp2(float x){ return __builtin_amdgcn_exp2f(x); }
__device__ __forceinline__ float frcp (float x){ return __builtin_amdgcn_rcpf(x); }
__device__ __forceinline__ float ftanh(float x){
    return fmaf(2.f, frcp(1.f + fexp2(-2.88539008f * x)), -1.f);
}
__device__ __forceinline__ float fsig(float x){
    return frcp(1.f + fexp2(-1.44269504f * x));
}
__device__ __forceinline__ u32 cvtpk(float lo, float hi){
    u32 r; asm("v_cvt_pk_bf16_f32 %0, %1, %2" : "=v"(r) : "v"(lo), "v"(hi)); return r;
}
__device__ __forceinline__ float ubf_lo(u32 w){ union{u32 i; float f;} v; v.i = w << 16;         return v.f; }
__device__ __forceinline__ float ubf_hi(u32 w){ union{u32 i; float f;} v; v.i = w & 0xffff0000u; return v.f; }
// VALU cross-lane swaps (gfx950): 32 = swap high half of a with low half of b;
// 16 = swap odd 16-lane rows of a with even 16-lane rows of b.
__device__ __forceinline__ void pswap32(u32& a, u32& b){
    asm("v_permlane32_swap_b32 %0, %1" : "+v"(a), "+v"(b));
}
__device__ __forceinline__ void pswap16(u32& a, u32& b){
    asm("v_permlane16_swap_b32 %0, %1" : "+v"(a), "+v"(b));
}
#define MFMA(A,B,C) __builtin_amdgcn_mfma_f32_16x16x32_bf16((A),(B),(C),0,0,0)

// pack a D-frag (4 f32, rows 4G+[0..4) of col c) into hi/lo bf16x2 words
__device__ __forceinline__ void pack4(v4f d, u32& Ah, u32& Bh, u32& Al, u32& Bl){
    Ah = cvtpk(d[0], d[1]);
    Bh = cvtpk(d[2], d[3]);
    Al = cvtpk(d[0] - ubf_lo(Ah), d[1] - ubf_hi(Ah));
    Bl = cvtpk(d[2] - ubf_lo(Bh), d[3] - ubf_hi(Bh));
}
// words -> B-frag [x_hi (k0..15) | x_lo (k16..31)] via permlane transpose
__device__ __forceinline__ v8s swizB(u32 Ah, u32 Bh, u32 Al, u32 Bl){
    pswap32(Ah, Al); pswap16(Ah, Al);   // Ah -> W0 [Ah0,Ah2,Al0,Al2], Al -> W2
    pswap32(Bh, Bl); pswap16(Bh, Bl);   // Bh -> W1, Bl -> W3
    FragU F; F.w[0] = Ah; F.w[1] = Bh; F.w[2] = Al; F.w[3] = Bl;
    return F.s;
}
__device__ __forceinline__ v8s reB(v4f d){
    u32 Ah, Bh, Al, Bl; pack4(d, Ah, Bh, Al, Bl);
    return swizB(Ah, Bh, Al, Bl);
}
// Split weight A-frags: A1=[W_hi|W_hi], A2=[W_lo|0]. W row-major [R x ld].
__device__ __forceinline__ void loadAsplit(const float* W, int ld, int R, int C,
                                           v8s& A1, v8s& A2){
    const int r = threadIdx.x & 15, G = threadIdx.x >> 4;
    const int g2 = G & 1;
    FragU H, L;
#pragma unroll
    for (int p = 0; p < 4; ++p){
        const int k0 = 8*g2 + 2*p;
        const float a = (r < R && k0     < C) ? W[r*ld + k0]     : 0.f;
        const float b = (r < R && k0 + 1 < C) ? W[r*ld + k0 + 1] : 0.f;
        const u32 h = cvtpk(a, b);
        const u32 l = cvtpk(a - ubf_lo(h), b - ubf_hi(h));
        H.w[p] = h;
        L.w[p] = (G < 2) ? l : 0u;
    }
    A1 = H.s; A2 = L.s;
}
// Leaf weight A-frag: A=[W|W] (pairs with B=[x_hi|x_lo] for full input precision)
__device__ __forceinline__ v8s loadA1(const float* W, int ld, int R, int C){
    const int r = threadIdx.x & 15, G = threadIdx.x >> 4;
    const int g2 = G & 1;
    FragU H;
#pragma unroll
    for (int p = 0; p < 4; ++p){
        const int k0 = 8*g2 + 2*p;
        const float a = (r < R && k0     < C) ? W[r*ld + k0]     : 0.f;
        const float b = (r < R && k0 + 1 < C) ? W[r*ld + k0 + 1] : 0.f;
        H.w[p] = cvtpk(a, b);
    }
    return H.s;
}
__device__ __forceinline__ v4f loadCbias(const float* bsrc, int R){
    const int m = threadIdx.x >> 4;
    v4f c;
#pragma unroll
    for (int j = 0; j < 4; ++j){
        const int idx = 4*m + j;
        c[j] = (idx < R) ? bsrc[idx] : 0.f;
    }
    return c;
}
__device__ __forceinline__ v4f tanh4(v4f a){
    v4f r;
#pragma unroll
    for (int j = 0; j < 4; ++j) r[j] = ftanh(a[j]);
    return r;
}
__device__ __forceinline__ void st2(float* p, float a, float b){
    v2f v; v[0] = a; v[1] = b; *(v2f*)p = v;
}
// Read stashed h pack-words for step t: they ARE the B-frag verbatim.
// ch 34+4G..37+4G per lane: G=0:[Ah0,Bh0,Ah1,Bh1] G=1:[Ah2,Bh2,Ah3,Bh3]
// G=2:[Al0,Bl0,Al1,Bl1] G=3:[Al2,Bl2,Al3,Bl3]  == W0..W3 rows of [hh|hl].
__device__ __forceinline__ v8s loadHfrag(const float* out, int t, int bc, int G){
    const float* o = out + (size_t)(t*BATCH + bc) * OUTW;
    FragU F;
    v2u a = *(const v2u*)(o + 34 + 4*G);
    v2u b = *(const v2u*)(o + 36 + 4*G);
    F.w[0] = a[0]; F.w[1] = a[1]; F.w[2] = b[0]; F.w[3] = b[1];
    return F.s;
}

__global__ __launch_bounds__(64)
void dkf_mfma_kernel(const float* __restrict__ x,   const float* __restrict__ eps_z,
                     const float* __restrict__ Wih, const float* __restrict__ Whh,
                     const float* __restrict__ bih, const float* __restrict__ bhh,
                     const float* __restrict__ cW1, const float* __restrict__ cb1,
                     const float* __restrict__ cW2, const float* __restrict__ cb2,
                     const float* __restrict__ eW1, const float* __restrict__ eb1,
                     const float* __restrict__ eW2, const float* __restrict__ eb2,
                     const float* __restrict__ dW1, const float* __restrict__ db1,
                     const float* __restrict__ dW2, const float* __restrict__ db2,
                     const float* __restrict__ tW1, const float* __restrict__ tb1,
                     const float* __restrict__ tW2, const float* __restrict__ tb2,
                     float* __restrict__ out)
{
    const int lane = threadIdx.x;
    const int c    = lane & 15;
    const int G    = lane >> 4;
    const int bc   = blockIdx.x * 16 + c;

    // ================= Phase 1: backward LSTM =================
    {
        v8s A1g[4], A2g[4];
#pragma unroll
        for (int g = 0; g < 4; ++g)
            loadAsplit(Whh + 256*g, 16, 16, 16, A1g[g], A2g[g]);
        v4f bc4[4];
#pragma unroll
        for (int g = 0; g < 4; ++g){
            v4f t;
#pragma unroll
            for (int j = 0; j < 4; ++j){
                const int idx = 16*g + 4*G + j;
                t[j] = bih[idx] + bhh[idx];
            }
            bc4[g] = t;
        }
        float wihr[4][4];
#pragma unroll
        for (int g = 0; g < 4; ++g)
#pragma unroll
            for (int j = 0; j < 4; ++j) wihr[g][j] = Wih[16*g + 4*G + j];

        v4f cst = {0.f, 0.f, 0.f, 0.f};
        FragU Z0; Z0.w[0]=Z0.w[1]=Z0.w[2]=Z0.w[3]=0u;
        v8s hb = Z0.s;                       // h B-frag [hh|hl]; h0 = 0
        float xv[2];
        xv[0] = x[(T_LEN-1)*BATCH + bc];
        xv[1] = x[(T_LEN-2)*BATCH + bc];

        for (int t2 = 0; t2 < T_LEN/2; ++t2){
#pragma unroll
            for (int q = 0; q < 2; ++q){
                const int t = T_LEN - 1 - 2*t2 - q;
                // C-in = bias + Wih*x (off the h-chain), then 2 chained MFMAs
                v4f ci, cf, cg, co;
#pragma unroll
                for (int j = 0; j < 4; ++j){
                    ci[j] = fmaf(wihr[0][j], xv[q], bc4[0][j]);
                    cf[j] = fmaf(wihr[1][j], xv[q], bc4[1][j]);
                    cg[j] = fmaf(wihr[2][j], xv[q], bc4[2][j]);
                    co[j] = fmaf(wihr[3][j], xv[q], bc4[3][j]);
                }
                v4f di  = MFMA(A1g[0], hb, ci); di  = MFMA(A2g[0], hb, di);
                v4f df  = MFMA(A1g[1], hb, cf); df  = MFMA(A2g[1], hb, df);
                v4f dg  = MFMA(A1g[2], hb, cg); dg  = MFMA(A2g[2], hb, dg);
                v4f doo = MFMA(A1g[3], hb, co); doo = MFMA(A2g[3], hb, doo);
                v4f hv;
#pragma unroll
                for (int j = 0; j < 4; ++j){
                    const float si = fsig(di[j]);
                    const float sf = fsig(df[j]);
                    const float tg = ftanh(dg[j]);
                    const float so = fsig(doo[j]);
                    cst[j] = fmaf(sf, cst[j], si * tg);
                    hv[j]  = so * ftanh(cst[j]);
                }
                u32 Ah, Bh, Al, Bl;
                pack4(hv, Ah, Bh, Al, Bl);
                {   // stash pack-words (phase 2 reads them back as B-frags)
                    float* o = out + (size_t)(t*BATCH + bc) * OUTW;
                    v2u sh; sh[0] = Ah; sh[1] = Bh;
                    v2u sl; sl[0] = Al; sl[1] = Bl;
                    *(v2u*)(o + 34 + 2*G) = sh;
                    *(v2u*)(o + 42 + 2*G) = sl;
                }
                hb = swizB(Ah, Bh, Al, Bl);
                const int tn = (t >= 2) ? (t - 2) : 0;
                xv[q] = x[tn*BATCH + bc];
            }
        }
    }

    __threadfence();   // drain phase-1 stash stores before readback

    // ================= Phase 2: forward DKF scan + dec + tr =================
    v8s C1h1, C1h2; loadAsplit(cW1,       32, 16, 16, C1h1, C1h2);
    v8s C1z1, C1z2; loadAsplit(cW1 + 16,  32, 16, 16, C1z1, C1z2);
    v8s C21,  C22;  loadAsplit(cW2,       16,  8, 16, C21,  C22);
    v8s E11,  E12;  loadAsplit(eW1,        8, 16,  8, E11,  E12);
    v8s E2m1, E2m2; loadAsplit(eW2,       16, 16, 16, E2m1, E2m2);
    v8s E2v1, E2v2; loadAsplit(eW2 + 256, 16, 16, 16, E2v1, E2v2);
    v8s D1  = loadA1(dW1,       16, 16, 16);
    v8s D2  = loadA1(dW2,       16,  2, 16);
    v8s T1  = loadA1(tW1,       16, 16, 16);
    v8s T2m = loadA1(tW2,       16, 16, 16);
    v8s T2v = loadA1(tW2 + 256, 16, 16, 16);
    const v4f bC1  = loadCbias(cb1, 16);
    const v4f bC2  = loadCbias(cb2,  8);
    const v4f bE1  = loadCbias(eb1, 16);
    const v4f bE2m = loadCbias(eb2, 16);
    const v4f bE2v = loadCbias(eb2 + 16, 16);
    const v4f bD1  = loadCbias(db1, 16);
    const v4f bD2  = loadCbias(db2,  2);
    const v4f bT1  = loadCbias(tb1, 16);
    const v4f bT2m = loadCbias(tb2, 16);
    const v4f bT2v = loadCbias(tb2 + 16, 16);

    FragU Z1; Z1.w[0]=Z1.w[1]=Z1.w[2]=Z1.w[3]=0u;
    v8s zb = Z1.s;                           // z_prev B-frag [zh|zl]; z0 = 0

    v8s hbr[2];
    v4f epr[2];
    hbr[0] = loadHfrag(out, 0, bc, G);
    hbr[1] = loadHfrag(out, 1, bc, G);
    epr[0] = *(const v4f*)(eps_z + (size_t)(0*BATCH + bc)*16 + 4*G);
    epr[1] = *(const v4f*)(eps_z + (size_t)(1*BATCH + bc)*16 + 4*G);

    for (int t2 = 0; t2 < T_LEN/2; ++t2){
#pragma unroll
        for (int q = 0; q < 2; ++q){
            const int t = 2*t2 + q;
            float* o = out + (size_t)(t*BATCH + bc) * OUTW;
            const v8s hb = hbr[q];
            const v4f ep = epr[q];
            {   // prefetch (+2)
                int tn = t + 2; if (tn >= T_LEN) tn = T_LEN - 1;
                hbr[q] = loadHfrag(out, tn, bc, G);
                epr[q] = *(const v4f*)(eps_z + (size_t)(tn*BATCH + bc)*16 + 4*G);
            }
            // ---- tr branch (uses z_prev; off the z-critical path) ----
            v4f dt1 = MFMA(T1, zb, bT1);
            v4f at  = tanh4(dt1);
            v8s atb = reB(at);
            v4f dmt = MFMA(T2m, atb, bT2m);
            v4f dlt = MFMA(T2v, atb, bT2v);
            // ---- main chain (h-part first so z-chain sees only 2 MFMAs) ----
            v4f d1 = MFMA(C1h1, hb, bC1);
            d1 = MFMA(C1h2, hb, d1);
            d1 = MFMA(C1z1, zb, d1);
            d1 = MFMA(C1z2, zb, d1);
            v4f a1  = tanh4(d1);
            v8s a1b = reB(a1);
            v4f d2 = MFMA(C21, a1b, bC2); d2 = MFMA(C22, a1b, d2);
            v8s gb2 = reB(d2);
            v4f d3 = MFMA(E11, gb2, bE1); d3 = MFMA(E12, gb2, d3);
            v4f e1  = tanh4(d3);
            v8s e1b = reB(e1);
            v4f dmu = MFMA(E2m1, e1b, bE2m); dmu = MFMA(E2m2, e1b, dmu);
            v4f dlv = MFMA(E2v1, e1b, bE2v); dlv = MFMA(E2v2, e1b, dlv);
            // reparameterize: z = mu + eps * exp(0.5*logvar)
            v4f zv;
#pragma unroll
            for (int j = 0; j < 4; ++j){
                const float s = fexp2(0.72134752f * fminf(dlv[j], 40.f));
                zv[j] = fmaf(ep[j], s, dmu[j]);
            }
            zb = reB(zv);
            // ---- dec branch (uses new z; off-chain for next iter) ----
            v4f dd1 = MFMA(D1, zb, bD1);
            v4f ad  = tanh4(dd1);
            v8s adb = reB(ad);
            v4f dd2 = MFMA(D2, adb, bD2);
            // ---- stores ----
            st2(o +  2 + 4*G, dmu[0], dmu[1]); st2(o +  4 + 4*G, dmu[2], dmu[3]);
            st2(o + 18 + 4*G, dlv[0], dlv[1]); st2(o + 20 + 4*G, dlv[2], dlv[3]);
            st2(o + 34 + 4*G, dmt[0], dmt[1]); st2(o + 36 + 4*G, dmt[2], dmt[3]);
            st2(o + 50 + 4*G, dlt[0], dlt[1]); st2(o + 52 + 4*G, dlt[2], dlt[3]);
            if (lane < 16) st2(o, dd2[0], dd2[1]);   // mu_x, logvar_x
        }
    }
}

extern "C" void kernel_launch(void* const* d_in, const int* in_sizes, int n_in,
                              void* d_out, int out_size, void* d_ws, size_t ws_size,
                              hipStream_t stream) {
    (void)in_sizes; (void)n_in; (void)out_size; (void)d_ws; (void)ws_size;
    const float* x     = (const float*)d_in[0];
    const float* eps_z = (const float*)d_in[1];
    const float* Wih   = (const float*)d_in[2];
    const float* Whh   = (const float*)d_in[3];
    const float* bih   = (const float*)d_in[4];
    const float* bhh   = (const float*)d_in[5];
    const float* cW1   = (const float*)d_in[6];
    const float* cb1   = (const float*)d_in[7];
    const float* cW2   = (const float*)d_in[8];
    const float* cb2   = (const float*)d_in[9];
    const float* eW1   = (const float*)d_in[10];
    const float* eb1   = (const float*)d_in[11];
    const float* eW2   = (const float*)d_in[12];
    const float* eb2   = (const float*)d_in[13];
    const float* dW1   = (const float*)d_in[14];
    const float* db1   = (const float*)d_in[15];
    const float* dW2   = (const float*)d_in[16];
    const float* db2   = (const float*)d_in[17];
    const float* tW1   = (const float*)d_in[18];
    const float* tb1   = (const float*)d_in[19];
    const float* tW2   = (const float*)d_in[20];
    const float* tb2   = (const float*)d_in[21];

    dkf_mfma_kernel<<<BATCH/16, 64, 0, stream>>>(
        x, eps_z, Wih, Whh, bih, bhh,
        cW1, cb1, cW2, cb2, eW1, eb1, eW2, eb2,
        dW1, db1, dW2, db2, tW1, tb1, tW2, tb2,
        (float*)d_out);
}

// Round 4
// 927.345 us; speedup vs baseline: 1.7873x; 1.0825x over previous
//
#include <hip/hip_runtime.h>

// Deep Kalman Filter via MFMA + permlane swaps; latency-restructured.
// Dims: X=1, Z=16, H=16, G=8, I=16, T=512, B=2048
//
// 16 batch elements per wave (batch on the mfma N dim), 128 blocks x 64 thr.
// Wall time = one wave's serial chain over 1024 timesteps. r3 measured
// ~3360 cy/step-pair => MFMA dependent latency ~200cy dominates; this version
// minimizes DEPENDENT MFMA hops on the loop-carried chain:
//  - comb2+enc1 folded:  e1 = tanh(M@a1 + b'),  M = eW1@cW2 (no tanh between)
//  - split-precision pairs as PARALLEL MFMAs (C=bias / C=0) + VALU add
//  - d1's h-part precomputed one iteration early (h is prefetched)
//  - dec head deferred one iteration (computed at next iter's head as fill)
//  => z-chain = 3 MFMA hops + 2 tanh + 3 reB + reparam  (was 10 hops)
//
// Layouts (guide-verified 16x16x32 bf16):
//   A frag: row = lane&15, k = 8*(lane>>4)+[0..8)
//   B frag: col = lane&15, k = 8*(lane>>4)+[0..8)
//   C/D   : col = lane&15, row = 4*(lane>>4)+reg
// Precision: activations split x=x_hi+x_lo; B=[x_hi|x_lo]; split layers use
// A1=[W_hi|W_hi] (C=bias) + A2=[W_lo|0] (C=0), summed on VALU. Leaf layers
// A=[W|W] in one MFMA. h_seq stashed as pack-words in out ch34..49 (read back
// verbatim as B-frags), later overwritten by mu_tr/logvar_tr.
#define T_LEN 512
#define BATCH 2048
#define OUTW  66

typedef unsigned int u32;
typedef short v8s __attribute__((ext_vector_type(8)));
typedef float v4f __attribute__((ext_vector_type(4)));
typedef float v2f __attribute__((ext_vector_type(2)));
typedef u32   v2u __attribute__((ext_vector_type(2)));

union FragU { v8s s; u32 w[4]; };

__device__ __forceinline__ float fexp2(float x){ return __builtin_amdgcn_exp2f(x); }
__device__ __forceinline__ float frcp (float x){ return __builtin_amdgcn_rcpf(x); }
__device__ __forceinline__ float ftanh(float x){
    return fmaf(2.f, frcp(1.f + fexp2(-2.88539008f * x)), -1.f);
}
__device__ __forceinline__ float fsig(float x){
    return frcp(1.f + fexp2(-1.44269504f * x));
}
__device__ __forceinline__ u32 cvtpk(float lo, float hi){
    u32 r; asm("v_cvt_pk_bf16_f32 %0, %1, %2" : "=v"(r) : "v"(lo), "v"(hi)); return r;
}
__device__ __forceinline__ float ubf_lo(u32 w){ union{u32 i; float f;} v; v.i = w << 16;         return v.f; }
__device__ __forceinline__ float ubf_hi(u32 w){ union{u32 i; float f;} v; v.i = w & 0xffff0000u; return v.f; }
__device__ __forceinline__ void pswap32(u32& a, u32& b){
    asm("v_permlane32_swap_b32 %0, %1" : "+v"(a), "+v"(b));
}
__device__ __forceinline__ void pswap16(u32& a, u32& b){
    asm("v_permlane16_swap_b32 %0, %1" : "+v"(a), "+v"(b));
}
#define MFMA(A,B,C) __builtin_amdgcn_mfma_f32_16x16x32_bf16((A),(B),(C),0,0,0)

__device__ __forceinline__ void pack4(v4f d, u32& Ah, u32& Bh, u32& Al, u32& Bl){
    Ah = cvtpk(d[0], d[1]);
    Bh = cvtpk(d[2], d[3]);
    Al = cvtpk(d[0] - ubf_lo(Ah), d[1] - ubf_hi(Ah));
    Bl = cvtpk(d[2] - ubf_lo(Bh), d[3] - ubf_hi(Bh));
}
__device__ __forceinline__ v8s swizB(u32 Ah, u32 Bh, u32 Al, u32 Bl){
    pswap32(Ah, Al); pswap16(Ah, Al);
    pswap32(Bh, Bl); pswap16(Bh, Bl);
    FragU F; F.w[0] = Ah; F.w[1] = Bh; F.w[2] = Al; F.w[3] = Bl;
    return F.s;
}
__device__ __forceinline__ v8s reB(v4f d){
    u32 Ah, Bh, Al, Bl; pack4(d, Ah, Bh, Al, Bl);
    return swizB(Ah, Bh, Al, Bl);
}
__device__ __forceinline__ void loadAsplit(const float* W, int ld, int R, int C,
                                           v8s& A1, v8s& A2){
    const int r = threadIdx.x & 15, G = threadIdx.x >> 4;
    const int g2 = G & 1;
    FragU H, L;
#pragma unroll
    for (int p = 0; p < 4; ++p){
        const int k0 = 8*g2 + 2*p;
        const float a = (r < R && k0     < C) ? W[r*ld + k0]     : 0.f;
        const float b = (r < R && k0 + 1 < C) ? W[r*ld + k0 + 1] : 0.f;
        const u32 h = cvtpk(a, b);
        const u32 l = cvtpk(a - ubf_lo(h), b - ubf_hi(h));
        H.w[p] = h;
        L.w[p] = (G < 2) ? l : 0u;
    }
    A1 = H.s; A2 = L.s;
}
__device__ __forceinline__ v8s loadA1(const float* W, int ld, int R, int C){
    const int r = threadIdx.x & 15, G = threadIdx.x >> 4;
    const int g2 = G & 1;
    FragU H;
#pragma unroll
    for (int p = 0; p < 4; ++p){
        const int k0 = 8*g2 + 2*p;
        const float a = (r < R && k0     < C) ? W[r*ld + k0]     : 0.f;
        const float b = (r < R && k0 + 1 < C) ? W[r*ld + k0 + 1] : 0.f;
        H.w[p] = cvtpk(a, b);
    }
    return H.s;
}
// Composite M = eW1(16x8) @ cW2(8x16), split A-frags.
__device__ __forceinline__ void loadMsplit(const float* eW1, const float* cW2,
                                           v8s& A1, v8s& A2){
    const int r = threadIdx.x & 15, G = threadIdx.x >> 4;
    const int g2 = G & 1;
    FragU H, L;
#pragma unroll
    for (int p = 0; p < 4; ++p){
        const int k0 = 8*g2 + 2*p;
        float a = 0.f, b = 0.f;
#pragma unroll
        for (int j = 0; j < 8; ++j){
            a = fmaf(eW1[r*8 + j], cW2[j*16 + k0],     a);
            b = fmaf(eW1[r*8 + j], cW2[j*16 + k0 + 1], b);
        }
        const u32 h = cvtpk(a, b);
        const u32 l = cvtpk(a - ubf_lo(h), b - ubf_hi(h));
        H.w[p] = h;
        L.w[p] = (G < 2) ? l : 0u;
    }
    A1 = H.s; A2 = L.s;
}
__device__ __forceinline__ v4f loadCbias(const float* bsrc, int R){
    const int m = threadIdx.x >> 4;
    v4f c;
#pragma unroll
    for (int j = 0; j < 4; ++j){
        const int idx = 4*m + j;
        c[j] = (idx < R) ? bsrc[idx] : 0.f;
    }
    return c;
}
__device__ __forceinline__ v4f tanh4s(v4f a, v4f b){
    v4f r;
#pragma unroll
    for (int j = 0; j < 4; ++j) r[j] = ftanh(a[j] + b[j]);
    return r;
}
__device__ __forceinline__ v4f tanh4(v4f a){
    v4f r;
#pragma unroll
    for (int j = 0; j < 4; ++j) r[j] = ftanh(a[j]);
    return r;
}
__device__ __forceinline__ void st2(float* p, float a, float b){
    v2f v; v[0] = a; v[1] = b; *(v2f*)p = v;
}
__device__ __forceinline__ v8s loadHfrag(const float* out, int t, int bc, int G){
    const float* o = out + (size_t)(t*BATCH + bc) * OUTW;
    FragU F;
    v2u a = *(const v2u*)(o + 34 + 4*G);
    v2u b = *(const v2u*)(o + 36 + 4*G);
    F.w[0] = a[0]; F.w[1] = a[1]; F.w[2] = b[0]; F.w[3] = b[1];
    return F.s;
}

__global__ __launch_bounds__(64, 1)
void dkf_mfma_kernel(const float* __restrict__ x,   const float* __restrict__ eps_z,
                     const float* __restrict__ Wih, const float* __restrict__ Whh,
                     const float* __restrict__ bih, const float* __restrict__ bhh,
                     const float* __restrict__ cW1, const float* __restrict__ cb1,
                     const float* __restrict__ cW2, const float* __restrict__ cb2,
                     const float* __restrict__ eW1, const float* __restrict__ eb1,
                     const float* __restrict__ eW2, const float* __restrict__ eb2,
                     const float* __restrict__ dW1, const float* __restrict__ db1,
                     const float* __restrict__ dW2, const float* __restrict__ db2,
                     const float* __restrict__ tW1, const float* __restrict__ tb1,
                     const float* __restrict__ tW2, const float* __restrict__ tb2,
                     float* __restrict__ out)
{
    const int lane = threadIdx.x;
    const int c    = lane & 15;
    const int G    = lane >> 4;
    const int bc   = blockIdx.x * 16 + c;
    const v4f z4   = {0.f, 0.f, 0.f, 0.f};

    // ================= Phase 1: backward LSTM =================
    {
        v8s A1g[4], A2g[4];
#pragma unroll
        for (int g = 0; g < 4; ++g)
            loadAsplit(Whh + 256*g, 16, 16, 16, A1g[g], A2g[g]);
        v4f bc4[4];
#pragma unroll
        for (int g = 0; g < 4; ++g){
            v4f t;
#pragma unroll
            for (int j = 0; j < 4; ++j){
                const int idx = 16*g + 4*G + j;
                t[j] = bih[idx] + bhh[idx];
            }
            bc4[g] = t;
        }
        float wihr[4][4];
#pragma unroll
        for (int g = 0; g < 4; ++g)
#pragma unroll
            for (int j = 0; j < 4; ++j) wihr[g][j] = Wih[16*g + 4*G + j];

        v4f cst = {0.f, 0.f, 0.f, 0.f};
        FragU Z0; Z0.w[0]=Z0.w[1]=Z0.w[2]=Z0.w[3]=0u;
        v8s hb = Z0.s;
        float xr[4];
#pragma unroll
        for (int i = 0; i < 4; ++i) xr[i] = x[(T_LEN-1-i)*BATCH + bc];

        for (int t4 = 0; t4 < T_LEN/4; ++t4) {
#pragma unroll
            for (int q = 0; q < 4; ++q) {
                const int t = T_LEN - 1 - 4*t4 - q;
                v4f ci, cf, cg, co;
#pragma unroll
                for (int j = 0; j < 4; ++j){
                    ci[j] = fmaf(wihr[0][j], xr[q], bc4[0][j]);
                    cf[j] = fmaf(wihr[1][j], xr[q], bc4[1][j]);
                    cg[j] = fmaf(wihr[2][j], xr[q], bc4[2][j]);
                    co[j] = fmaf(wihr[3][j], xr[q], bc4[3][j]);
                }
                // 8 INDEPENDENT MFMAs (latencies overlap), summed on VALU
                v4f ui  = MFMA(A1g[0], hb, ci);  v4f vi  = MFMA(A2g[0], hb, z4);
                v4f uf  = MFMA(A1g[1], hb, cf);  v4f vf  = MFMA(A2g[1], hb, z4);
                v4f ug  = MFMA(A1g[2], hb, cg);  v4f vg  = MFMA(A2g[2], hb, z4);
                v4f uo  = MFMA(A1g[3], hb, co);  v4f vo  = MFMA(A2g[3], hb, z4);
                v4f hv;
#pragma unroll
                for (int j = 0; j < 4; ++j){
                    const float si = fsig(ui[j] + vi[j]);
                    const float sf = fsig(uf[j] + vf[j]);
                    const float tg = ftanh(ug[j] + vg[j]);
                    const float so = fsig(uo[j] + vo[j]);
                    cst[j] = fmaf(sf, cst[j], si * tg);
                    hv[j]  = so * ftanh(cst[j]);
                }
                u32 Ah, Bh, Al, Bl;
                pack4(hv, Ah, Bh, Al, Bl);
                {
                    float* o = out + (size_t)(t*BATCH + bc) * OUTW;
                    v2u sh; sh[0] = Ah; sh[1] = Bh;
                    v2u sl; sl[0] = Al; sl[1] = Bl;
                    *(v2u*)(o + 34 + 2*G) = sh;
                    *(v2u*)(o + 42 + 2*G) = sl;
                }
                hb = swizB(Ah, Bh, Al, Bl);
                const int tn = (t >= 4) ? (t - 4) : 0;
                xr[q] = x[tn*BATCH + bc];
            }
        }
    }

    __threadfence();   // drain phase-1 stash stores before readback

    // ================= Phase 2: forward DKF scan + heads =================
    v8s C1h1, C1h2; loadAsplit(cW1,       32, 16, 16, C1h1, C1h2);
    v8s C1z1, C1z2; loadAsplit(cW1 + 16,  32, 16, 16, C1z1, C1z2);
    v8s M1,   M2;   loadMsplit(eW1, cW2, M1, M2);          // folded comb2+enc1
    v8s E2m1, E2m2; loadAsplit(eW2,       16, 16, 16, E2m1, E2m2);
    v8s E2v1, E2v2; loadAsplit(eW2 + 256, 16, 16, 16, E2v1, E2v2);
    v8s D1  = loadA1(dW1,       16, 16, 16);
    v8s D2  = loadA1(dW2,       16,  2, 16);
    v8s T1  = loadA1(tW1,       16, 16, 16);
    v8s T2m = loadA1(tW2,       16, 16, 16);
    v8s T2v = loadA1(tW2 + 256, 16, 16, 16);
    const v4f bC1  = loadCbias(cb1, 16);
    const v4f bE2m = loadCbias(eb2, 16);
    const v4f bE2v = loadCbias(eb2 + 16, 16);
    const v4f bD1  = loadCbias(db1, 16);
    const v4f bD2  = loadCbias(db2,  2);
    const v4f bT1  = loadCbias(tb1, 16);
    const v4f bT2m = loadCbias(tb2, 16);
    const v4f bT2v = loadCbias(tb2 + 16, 16);
    v4f bMp;   // b' = eb1 + eW1 @ cb2
#pragma unroll
    for (int j = 0; j < 4; ++j){
        const int r = 4*G + j;
        float s = eb1[r];
#pragma unroll
        for (int k = 0; k < 8; ++k) s = fmaf(eW1[r*8 + k], cb2[k], s);
        bMp[j] = s;
    }

    FragU Z1; Z1.w[0]=Z1.w[1]=Z1.w[2]=Z1.w[3]=0u;
    v8s zb = Z1.s;                       // z_{t-1} B-frag; z_{-1}=0

    v8s hbr[4];
    v4f epr[4];
#pragma unroll
    for (int i = 0; i < 4; ++i){
        hbr[i] = loadHfrag(out, i, bc, G);
        epr[i] = *(const v4f*)(eps_z + (size_t)(i*BATCH + bc)*16 + 4*G);
    }
    // dh for t=0 (h-part of comb1, off the z-chain)
    v4f dh = MFMA(C1h1, hbr[0], bC1);
    dh = MFMA(C1h2, hbr[0], dh);

    for (int t4 = 0; t4 < T_LEN/4; ++t4){
#pragma unroll
        for (int q = 0; q < 4; ++q){
            const int t = 4*t4 + q;
            float* o = out + (size_t)(t*BATCH + bc) * OUTW;
            const v4f ep = epr[q];
            // ---- z-chain head: comb1 z-part (parallel pair) ----
            v4f d1u = MFMA(C1z1, zb, dh);
            v4f d1v = MFMA(C1z2, zb, z4);
            // ---- fill: tr(t) and deferred dec(t-1), both on entry zb ----
            v4f t1  = MFMA(T1, zb, bT1);
            v4f du  = MFMA(D1, zb, bD1);
            // ---- fill: prefetch t+4, next-iter dh (h(t+1) prefetched) ----
            {
                int tn = t + 4; if (tn >= T_LEN) tn = T_LEN - 1;
                hbr[q] = loadHfrag(out, tn, bc, G);
                epr[q] = *(const v4f*)(eps_z + (size_t)(tn*BATCH + bc)*16 + 4*G);
            }
            {
                const v8s hbn = hbr[(q + 1) & 3];   // h(t+1)
                v4f nh = MFMA(C1h1, hbn, bC1);
                nh = MFMA(C1h2, hbn, nh);
                dh = nh;
            }
            v4f at  = tanh4(t1);
            v4f ad  = tanh4(du);
            v8s atb = reB(at);
            v8s adb = reB(ad);
            v4f dmt = MFMA(T2m, atb, bT2m);
            v4f dlt = MFMA(T2v, atb, bT2v);
            v4f dd2 = MFMA(D2, adb, bD2);
            // ---- z-chain: a1 -> (M fold) e1 -> enc2 -> reparam ----
            v4f a1  = tanh4s(d1u, d1v);
            v8s a1b = reB(a1);
            v4f eu  = MFMA(M1, a1b, bMp);
            v4f ev  = MFMA(M2, a1b, z4);
            v4f e1  = tanh4s(eu, ev);
            v8s e1b = reB(e1);
            v4f muu = MFMA(E2m1, e1b, bE2m);
            v4f muv = MFMA(E2m2, e1b, z4);
            v4f lvu = MFMA(E2v1, e1b, bE2v);
            v4f lvv = MFMA(E2v2, e1b, z4);
            v4f dmu, dlv, zv;
#pragma unroll
            for (int j = 0; j < 4; ++j){
                dmu[j] = muu[j] + muv[j];
                dlv[j] = lvu[j] + lvv[j];
                const float s = fexp2(0.72134752f * fminf(dlv[j], 40.f));
                zv[j] = fmaf(ep[j], s, dmu[j]);
            }
            zb = reB(zv);
            // ---- stores (off-chain) ----
            st2(o +  2 + 4*G, dmu[0], dmu[1]); st2(o +  4 + 4*G, dmu[2], dmu[3]);
            st2(o + 18 + 4*G, dlv[0], dlv[1]); st2(o + 20 + 4*G, dlv[2], dlv[3]);
            st2(o + 34 + 4*G, dmt[0], dmt[1]); st2(o + 36 + 4*G, dmt[2], dmt[3]);
            st2(o + 50 + 4*G, dlt[0], dlt[1]); st2(o + 52 + 4*G, dlt[2], dlt[3]);
            if (t > 0 && lane < 16){
                float* op = out + (size_t)((t-1)*BATCH + bc) * OUTW;
                st2(op, dd2[0], dd2[1]);        // mu_x, logvar_x for t-1
            }
        }
    }
    // epilogue: dec(T-1) on final zb
    {
        v4f du  = MFMA(D1, zb, bD1);
        v4f ad  = tanh4(du);
        v8s adb = reB(ad);
        v4f dd2 = MFMA(D2, adb, bD2);
        if (lane < 16){
            float* op = out + (size_t)((T_LEN-1)*BATCH + bc) * OUTW;
            st2(op, dd2[0], dd2[1]);
        }
    }
}

extern "C" void kernel_launch(void* const* d_in, const int* in_sizes, int n_in,
                              void* d_out, int out_size, void* d_ws, size_t ws_size,
                              hipStream_t stream) {
    (void)in_sizes; (void)n_in; (void)out_size; (void)d_ws; (void)ws_size;
    const float* x     = (const float*)d_in[0];
    const float* eps_z = (const float*)d_in[1];
    const float* Wih   = (const float*)d_in[2];
    const float* Whh   = (const float*)d_in[3];
    const float* bih   = (const float*)d_in[4];
    const float* bhh   = (const float*)d_in[5];
    const float* cW1   = (const float*)d_in[6];
    const float* cb1   = (const float*)d_in[7];
    const float* cW2   = (const float*)d_in[8];
    const float* cb2   = (const float*)d_in[9];
    const float* eW1   = (const float*)d_in[10];
    const float* eb1   = (const float*)d_in[11];
    const float* eW2   = (const float*)d_in[12];
    const float* eb2   = (const float*)d_in[13];
    const float* dW1   = (const float*)d_in[14];
    const float* db1   = (const float*)d_in[15];
    const float* dW2   = (const float*)d_in[16];
    const float* db2   = (const float*)d_in[17];
    const float* tW1   = (const float*)d_in[18];
    const float* tb1   = (const float*)d_in[19];
    const float* tW2   = (const float*)d_in[20];
    const float* tb2   = (const float*)d_in[21];

    dkf_mfma_kernel<<<BATCH/16, 64, 0, stream>>>(
        x, eps_z, Wih, Whh, bih, bhh,
        cW1, cb1, cW2, cb2, eW1, eb1, eW2, eb2,
        dW1, db1, dW2, db2, tW1, tb1, tW2, tb2,
        (float*)d_out);
}